// Round 1
// baseline (357.592 us; speedup 1.0000x reference)
//
#include <hip/hip_runtime.h>
#include <hip/hip_fp16.h>

#define TT   4096
#define GG   32
#define NTH  512
#define SM_BYTES 101440

__device__ __forceinline__ float centerF(int k){
    return (float)(-0.5 + (double)k * (1.0/7.0));
}

__device__ __forceinline__ float filt(int m, float ck){
    float f = (float)((m < TT/2) ? m : (m - TT)) * (1.0f/(float)TT);
    float d = (f - ck) * 8.0f;            // dist / bandwidth, bandwidth = 1/8
    return __expf(-0.5f * d * d);
}

// One Stockham radix-2 stage: 2048 butterflies, N=4096. sgn=-1 fwd, +1 inv.
__device__ __forceinline__ void fft_stage(const float* __restrict__ sr, const float* __restrict__ si,
                                          float* __restrict__ dr, float* __restrict__ di,
                                          int Ns, float sgn, int tid){
    const float PI_F = 3.14159265358979323846f;
#pragma unroll
    for (int u = 0; u < (TT/2)/NTH; ++u){
        int j = tid + u*NTH;
        float ar = sr[j],        ai = si[j];
        float br = sr[j+TT/2],   bi = si[j+TT/2];
        int   kk = j & (Ns-1);
        float ang = sgn * (PI_F * (float)kk / (float)Ns);
        float s, c;
        __sincosf(ang, &s, &c);
        float tr = br*c - bi*s;
        float ti = br*s + bi*c;
        int idxD = ((j & ~(Ns-1)) << 1) | kk;   // (j/Ns)*2Ns + j%Ns
        dr[idxD]     = ar + tr;  di[idxD]     = ai + ti;
        dr[idxD+Ns]  = ar - tr;  di[idxD+Ns]  = ai - ti;
    }
}

// W[m] = Z_k0[m] + i*Z_k1[m], Z_k = (X[m]F_k[m] + conj(X[N-m])F_k[N-m])/2, scaled by 1/N
__device__ __forceinline__ void makeW(const float* __restrict__ Xr, const float* __restrict__ Xi,
                                      int m, float ck0, float ck1, float& wr, float& wi){
    int mm = (TT - m) & (TT - 1);
    float xr = Xr[m],  xi = Xi[m];
    float yr = Xr[mm], yi = Xi[mm];
    float f0m = filt(m, ck0), f0n = filt(mm, ck0);
    float f1m = filt(m, ck1), f1n = filt(mm, ck1);
    const float sc = 0.5f / (float)TT;
    float z0r = (xr*f0m + yr*f0n) * sc;
    float z0i = (xi*f0m - yi*f0n) * sc;
    float z1r = (xr*f1m + yr*f1n) * sc;
    float z1i = (xi*f1m - yi*f1n) * sc;
    wr = z0r - z1i;
    wi = z0i + z1r;
}

__device__ __forceinline__ int wt_of(int r){ return r==0 ? 6 : (r==1 ? 2 : (r==2 ? 1 : 0)); }

// Lehmer code of stable argsort of (v0,v1,v2,v3) — register-only, 6 compares.
__device__ __forceinline__ int pattern_id(float v0, float v1, float v2, float v3){
    int c01 = (v0 <= v1), c02 = (v0 <= v2), c03 = (v0 <= v3);
    int c12 = (v1 <= v2), c13 = (v1 <= v3), c23 = (v2 <= v3);
    int r1 = c01 + (1-c12) + (1-c13);
    int r2 = c02 + c12 + (1-c23);
    int r3 = c03 + c13 + c23;
    int g1 = 1 - c01;
    int g2 = (1-c02) + (1-c12);
    int g3 = (1-c03) + (1-c13) + (1-c23);
    return wt_of(r1)*g1 + wt_of(r2)*g2 + wt_of(r3)*g3;
}

// Histogram the 576 transition bins for one mode (values in LDS array m[4096]).
__device__ __forceinline__ void pattern_hist(const float* __restrict__ m, unsigned* __restrict__ hist, int tid){
    int start = tid * (TT / NTH);                 // 8 transitions per thread
    int endt  = start + (TT / NTH);
    if (endt > TT - 4) endt = TT - 4;             // transitions t in [0, 4092)
    float w0 = m[start], w1 = m[start+1], w2 = m[start+2], w3 = m[start+3];
    int prev = pattern_id(w0, w1, w2, w3);
    int cur = -1; unsigned cnt = 0;
    for (int t = start; t < endt; ++t){
        w0 = w1; w1 = w2; w2 = w3; w3 = m[t+4];
        int nxt = pattern_id(w0, w1, w2, w3);
        int lin = prev*24 + nxt;
        if (lin == cur) { cnt++; }
        else { if (cnt) atomicAdd(&hist[cur], cnt); cur = lin; cnt = 1; }
        prev = nxt;
    }
    if (cnt) atomicAdd(&hist[cur], cnt);
}

template<int P>
__device__ __forceinline__ void process_pair(int tid,
        const float* Xr, const float* Xi,
        float* Ar, float* Ai, float* Br, float* Bi,
        float (&ce)[6][8],
        unsigned* hist, float* redbuf, float* mu_s, float* diag_s, float* cm_s){
    const int k0 = 2*P, k1 = 2*P+1;
    const float ck0 = centerF(k0), ck1 = centerF(k1);

    // IFFT stage 1 (Ns=1): build packed symmetrized spectrum on the fly, X -> A
#pragma unroll
    for (int u = 0; u < (TT/2)/NTH; ++u){
        int j = tid + u*NTH;
        float war, wai, wbr, wbi;
        makeW(Xr, Xi, j,        ck0, ck1, war, wai);
        makeW(Xr, Xi, j + TT/2, ck0, ck1, wbr, wbi);
        Ar[2*j]   = war + wbr;  Ai[2*j]   = wai + wbi;
        Ar[2*j+1] = war - wbr;  Ai[2*j+1] = wai - wbi;
    }
    __syncthreads();
    // stages 2..12 ping-pong A<->B, spectrum X untouched
    for (int s = 2; s <= 12; ++s){
        int Ns = 1 << (s-1);
        if (s & 1) fft_stage(Br, Bi, Ar, Ai, Ns, 1.f, tid);
        else       fft_stage(Ar, Ai, Br, Bi, Ns, 1.f, tid);
        __syncthreads();
    }
    // modes: mode_k0 = Br[t], mode_k1 = Bi[t]

    // means of energies
    {
        float s0 = 0.f, s1 = 0.f;
#pragma unroll
        for (int u = 0; u < TT/NTH; ++u){
            int t = tid + u*NTH;
            float m0 = Br[t], m1 = Bi[t];
            s0 += m0*m0; s1 += m1*m1;
        }
        for (int off = 32; off > 0; off >>= 1){
            s0 += __shfl_down(s0, off);
            s1 += __shfl_down(s1, off);
        }
        int lane = tid & 63, wid = tid >> 6;
        if (lane == 0){ redbuf[wid*16+0] = s0; redbuf[wid*16+1] = s1; }
        __syncthreads();
        if (tid < 2){
            float acc = 0.f;
            for (int w = 0; w < 8; ++w) acc += redbuf[w*16 + tid];
            mu_s[k0 + tid] = acc * (1.0f/(float)TT);
        }
        __syncthreads();
    }

    // ordinal-pattern transition histogram for both modes
    pattern_hist(Br, hist, tid);
    pattern_hist(Bi, hist, tid);

    // centered-energy products (diag + cross with previously stored modes)
    {
        const float mu0 = mu_s[k0], mu1 = mu_s[k1];
        float accd0 = 0.f, accd1 = 0.f, accx = 0.f;
        float accl[(4*P > 0) ? 4*P : 1];
#pragma unroll
        for (int i = 0; i < 4*P; ++i) accl[i] = 0.f;
#pragma unroll
        for (int u = 0; u < TT/NTH; ++u){
            int t = tid + u*NTH;
            float m0 = Br[t], m1 = Bi[t];
            float c0 = m0*m0 - mu0, c1 = m1*m1 - mu1;
            accd0 += c0*c0; accd1 += c1*c1; accx += c0*c1;
#pragma unroll
            for (int l = 0; l < 2*P; ++l){
                accl[2*l]   += ce[l][u] * c0;
                accl[2*l+1] += ce[l][u] * c1;
            }
            if (P < 3){ ce[k0][u] = c0; ce[k1][u] = c1; }
        }
        const int NACC = 3 + 4*P;
        float vals[NACC];
        vals[0] = accd0; vals[1] = accd1; vals[2] = accx;
#pragma unroll
        for (int i = 0; i < 4*P; ++i) vals[3+i] = accl[i];
#pragma unroll
        for (int a = 0; a < NACC; ++a){
            float v = vals[a];
            for (int off = 32; off > 0; off >>= 1) v += __shfl_down(v, off);
            if ((tid & 63) == 0) redbuf[(tid>>6)*16 + a] = v;
        }
        __syncthreads();
        if (tid < NACC){
            float acc = 0.f;
            for (int w = 0; w < 8; ++w) acc += redbuf[w*16 + tid];
            int a = tid;
            if      (a == 0) diag_s[k0] = acc;
            else if (a == 1) diag_s[k1] = acc;
            else if (a == 2) cm_s[k0*8 + k1] = acc;
            else {
                int l = (a-3) >> 1; int wch = (a-3) & 1;
                cm_s[l*8 + k0 + wch] = acc;
            }
        }
        __syncthreads();
    }
}

template<bool DIRECT>
__global__ __launch_bounds__(NTH, 1)
void fused_kernel(const float* __restrict__ hs, const float* __restrict__ pooled,
                  float* __restrict__ out){
    extern __shared__ float smem[];
    float* Xr = smem;            // 4096 each
    float* Xi = Xr + TT;
    float* Ar = Xi + TT;
    float* Ai = Ar + TT;
    float* Br = Ai + TT;
    float* Bi = Br + TT;                         // 24576 floats
    unsigned* hist = (unsigned*)(smem + 24576);  // 576 u32
    float* redbuf  = smem + 24576 + 576;         // 8 waves * 16
    float* mu_s    = redbuf + 128;               // 8
    float* diag_s  = mu_s + 8;                   // 8
    float* cm_s    = diag_s + 8;                 // 64

    int tid = threadIdx.x;
    int bg  = blockIdx.x;
    int b   = bg >> 5, g = bg & 31;

    for (int i = tid; i < 576; i += NTH) hist[i] = 0u;

    if (DIRECT){
        const float* base = hs + ((size_t)b * TT) * 512 + g * 16;
#pragma unroll
        for (int u = 0; u < TT/NTH; ++u){
            int t = tid + u*NTH;
            const float4* p = (const float4*)(base + (size_t)t * 512);
            float4 a = p[0], bb = p[1], cc = p[2], dd = p[3];
            float s = a.x+a.y+a.z+a.w + bb.x+bb.y+bb.z+bb.w
                    + cc.x+cc.y+cc.z+cc.w + dd.x+dd.y+dd.z+dd.w;
            Xr[t] = s * (1.0f/16.0f);
            Xi[t] = 0.f;
        }
    } else {
        const float* pp = pooled + (size_t)bg * TT;
#pragma unroll
        for (int u = 0; u < TT/NTH; ++u){
            int t = tid + u*NTH;
            Xr[t] = pp[t];
            Xi[t] = 0.f;
        }
    }
    __syncthreads();

    // forward FFT: ping-pong X <-> A, 12 stages, result lands in X
    for (int s = 1; s <= 12; ++s){
        int Ns = 1 << (s-1);
        if (s & 1) fft_stage(Xr, Xi, Ar, Ai, Ns, -1.f, tid);
        else       fft_stage(Ar, Ai, Xr, Xi, Ns, -1.f, tid);
        __syncthreads();
    }

    float ce[6][8];   // centered energies of modes 0..5 at t = tid + u*NTH
    process_pair<0>(tid, Xr, Xi, Ar, Ai, Br, Bi, ce, hist, redbuf, mu_s, diag_s, cm_s);
    process_pair<1>(tid, Xr, Xi, Ar, Ai, Br, Bi, ce, hist, redbuf, mu_s, diag_s, cm_s);
    process_pair<2>(tid, Xr, Xi, Ar, Ai, Br, Bi, ce, hist, redbuf, mu_s, diag_s, cm_s);
    process_pair<3>(tid, Xr, Xi, Ar, Ai, Br, Bi, ce, hist, redbuf, mu_s, diag_s, cm_s);

    __syncthreads();

    // tmptm: counts / 32736 (row sum is the constant 8*4092)
    float* tm_out = out + (size_t)bg * 576;
    for (int i = tid; i < 576; i += NTH)
        tm_out[i] = (float)hist[i] * (1.0f/32736.0f);

    // fmptm: 28 upper-tri correlations
    if (tid < 28){
        int q = tid, k = 0, cnt = 7, rem = q;
        while (rem >= cnt){ rem -= cnt; k++; cnt--; }
        int l = k + 1 + rem;
        float sk = fmaxf(sqrtf(diag_s[k] * (1.0f/4095.0f)), 1e-8f);
        float sl = fmaxf(sqrtf(diag_s[l] * (1.0f/4095.0f)), 1e-8f);
        out[294912 + (size_t)bg*28 + q] = cm_s[k*8 + l] / (4096.0f * sk * sl);
    }
}

// Coalesced pooling: [B,T,512] -> [B,G,T] group means
__global__ __launch_bounds__(256)
void pool_kernel(const float* __restrict__ hs, float* __restrict__ pooled){
    __shared__ float tile[32][65];
    int blk = blockIdx.x;               // 16 b * 64 chunks
    int b   = blk >> 6;
    int t0  = (blk & 63) << 6;
    int tid = threadIdx.x;
    int lane = tid & 63, wid = tid >> 6;
#pragma unroll
    for (int i = 0; i < 16; ++i){
        int tl = wid + i*4;
        int t  = t0 + tl;
        const float4* p = (const float4*)(hs + ((size_t)b * TT + t) * 512);
        float4 a = p[lane];
        float4 c = p[lane + 64];
        float pa = a.x+a.y+a.z+a.w;
        float pc = c.x+c.y+c.z+c.w;
        pa += __shfl_xor(pa, 1); pa += __shfl_xor(pa, 2);
        pc += __shfl_xor(pc, 1); pc += __shfl_xor(pc, 2);
        if ((lane & 3) == 0){
            int gq = lane >> 2;
            tile[gq][tl]      = pa * (1.0f/16.0f);
            tile[gq + 16][tl] = pc * (1.0f/16.0f);
        }
    }
    __syncthreads();
    for (int idx = tid; idx < 2048; idx += 256){
        int g = idx >> 6, tt = idx & 63;
        pooled[((size_t)b * 32 + g) * TT + t0 + tt] = tile[g][tt];
    }
}

extern "C" void kernel_launch(void* const* d_in, const int* in_sizes, int n_in,
                              void* d_out, int out_size, void* d_ws, size_t ws_size,
                              hipStream_t stream){
    const float* hs = (const float*)d_in[0];
    float* out = (float*)d_out;
    const size_t poolBytes = (size_t)512 * TT * sizeof(float);   // 8.4 MB

    if (d_ws && ws_size >= poolBytes){
        float* pooled = (float*)d_ws;
        pool_kernel<<<1024, 256, 0, stream>>>(hs, pooled);
        hipFuncSetAttribute((const void*)fused_kernel<false>,
                            hipFuncAttributeMaxDynamicSharedMemorySize, SM_BYTES);
        fused_kernel<false><<<512, NTH, SM_BYTES, stream>>>(hs, pooled, out);
    } else {
        hipFuncSetAttribute((const void*)fused_kernel<true>,
                            hipFuncAttributeMaxDynamicSharedMemorySize, SM_BYTES);
        fused_kernel<true><<<512, NTH, SM_BYTES, stream>>>(hs, nullptr, out);
    }
}

// Round 2
// 307.298 us; speedup vs baseline: 1.1637x; 1.1637x over previous
//
#include <hip/hip_runtime.h>
#include <hip/hip_fp16.h>

#define TT   4096
#define NTH  512
#define ARR  4224                       // 4096 + skew padding (SK(4095)=4222)
#define SK(e) ((e) + ((e) >> 5))
#define SM_FLOATS (4*ARR + 1152 + 44)   // A,B (re/im) + 2x hist + res
#define SM_BYTES  (SM_FLOATS * 4)

__device__ __forceinline__ float centerF(int k){
    return (float)(-0.5 + (double)k * (1.0/7.0));
}
__device__ __forceinline__ float freq_of(int m){
    return (float)((m < TT/2) ? m : (m - TT)) * (1.0f/(float)TT);
}
__device__ __forceinline__ float filtv(float f, float ck){
    float d = (f - ck) * 8.0f;
    return __expf(-0.5f * d * d);
}
// G_k[m] = (F_k[m] + F_k[N-m]) * 0.5/N   (Hermitian-input shortcut, includes 1/N)
__device__ __forceinline__ float Gval(int m, float ck){
    int mm = (TT - m) & (TT - 1);
    return (filtv(freq_of(m), ck) + filtv(freq_of(mm), ck)) * (0.5f/(float)TT);
}

struct C4 { float r0,i0,r1,i1,r2,i2,r3,i3; };

// radix-4 DIT butterfly; u = e^{+i*pi*kk/(2Ns)} (inverse-sign); SGN=-1 => fwd (conj applied inside)
template<int SGN>
__device__ __forceinline__ void bf4(float c0r,float c0i,float c1r,float c1i,
                                    float c2r,float c2i,float c3r,float c3i,
                                    float ur,float ui, C4& o){
    float u2r = ur*ur - ui*ui, u2i = 2.f*ur*ui;
    float u3r = u2r*ur - u2i*ui, u3i = u2r*ui + u2i*ur;
    if (SGN < 0){ ui = -ui; u2i = -u2i; u3i = -u3i; }
    float ar = u2r*c2r - u2i*c2i, ai = u2r*c2i + u2i*c2r;
    float br = ur*c1r  - ui*c1i,  bi = ur*c1i  + ui*c1r;
    float er = u3r*c3r - u3i*c3i, ei = u3r*c3i + u3i*c3r;
    float s0r = c0r+ar, s0i = c0i+ai, s1r = c0r-ar, s1i = c0i-ai;
    float s2r = br+er,  s2i = bi+ei,  s3r = br-er,  s3i = bi-ei;
    o.r0 = s0r+s2r; o.i0 = s0i+s2i;
    o.r2 = s0r-s2r; o.i2 = s0i-s2i;
    if (SGN > 0){ o.r1 = s1r-s3i; o.i1 = s1i+s3r; o.r3 = s1r+s3i; o.i3 = s1i-s3r; }
    else        { o.r1 = s1r+s3i; o.i1 = s1i-s3r; o.r3 = s1r-s3i; o.i3 = s1i+s3r; }
}

template<int SGN>
__device__ __forceinline__ void stageLDS(const float* __restrict__ sr, const float* __restrict__ si,
                                         float* __restrict__ dr, float* __restrict__ di,
                                         int Ns, float uAr,float uAi,float uBr,float uBi, int tid){
#pragma unroll
    for (int h = 0; h < 2; ++h){
        int j = tid + h*512;
        float ur = h ? uBr : uAr, ui = h ? uBi : uAi;
        int kk = j & (Ns-1);
        int base = ((j & ~(Ns-1)) << 2) | kk;
        C4 o;
        bf4<SGN>(sr[SK(j)],si[SK(j)], sr[SK(j+1024)],si[SK(j+1024)],
                 sr[SK(j+2048)],si[SK(j+2048)], sr[SK(j+3072)],si[SK(j+3072)], ur,ui,o);
        dr[SK(base)]       = o.r0;  di[SK(base)]       = o.i0;
        dr[SK(base+Ns)]    = o.r1;  di[SK(base+Ns)]    = o.i1;
        dr[SK(base+2*Ns)]  = o.r2;  di[SK(base+2*Ns)]  = o.i2;
        dr[SK(base+3*Ns)]  = o.r3;  di[SK(base+3*Ns)]  = o.i3;
    }
}

__device__ __forceinline__ int wt_of(int r){ return r==0 ? 6 : (r==1 ? 2 : (r==2 ? 1 : 0)); }

// Lehmer code of stable argsort — register-only, 6 compares (verified round 1)
__device__ __forceinline__ int pattern_id(float v0, float v1, float v2, float v3){
    int c01 = (v0 <= v1), c02 = (v0 <= v2), c03 = (v0 <= v3);
    int c12 = (v1 <= v2), c13 = (v1 <= v3), c23 = (v2 <= v3);
    int r1 = c01 + (1-c12) + (1-c13);
    int r2 = c02 + c12 + (1-c23);
    int r3 = c03 + c13 + c23;
    int g1 = 1 - c01;
    int g2 = (1-c02) + (1-c12);
    int g3 = (1-c03) + (1-c13) + (1-c23);
    return wt_of(r1)*g1 + wt_of(r2)*g2 + wt_of(r3)*g3;
}

__device__ __forceinline__ int DIDX(int k, int l){   // res index of D_kl, k<=l
    return 8 + k*8 + l - (k*(k+1))/2;
}

__device__ __forceinline__ void reduce_to(float v, float* res, int idx, int tid){
#pragma unroll
    for (int off = 32; off; off >>= 1) v += __shfl_xor(v, off);
    if ((tid & 63) == 0) atomicAdd(&res[idx], v);
}

template<int P>
__device__ __forceinline__ void process_pair(int tid,
        float* Ar, float* Ai, float* Br, float* Bi,
        unsigned* hist, float* res,
        const float (&xr)[8], const float (&xi)[8],
        __half2 (&est)[6][4],
        float t4r,float t4i,float t16r,float t16i,float t64r,float t64i,
        float t256r,float t256i,float tAr,float tAi,float tBr,float tBi){
    const float ck0 = centerF(2*P), ck1 = centerF(2*P+1);

    // stage 0 (Ns=1): registers (X * (G0 + i*G1)) -> A
#pragma unroll
    for (int h = 0; h < 2; ++h){
        int j = tid + h*512;
        float cr[4], ci[4];
#pragma unroll
        for (int q = 0; q < 4; ++q){
            int v = 2*q + h;
            int m = j + 1024*q;
            float g0 = Gval(m, ck0), g1 = Gval(m, ck1);
            cr[q] = xr[v]*g0 - xi[v]*g1;
            ci[q] = xi[v]*g0 + xr[v]*g1;
        }
        C4 o; bf4<1>(cr[0],ci[0],cr[1],ci[1],cr[2],ci[2],cr[3],ci[3], 1.f,0.f, o);
        int base = 4*j;
        Ar[SK(base)]   = o.r0;  Ai[SK(base)]   = o.i0;
        Ar[SK(base+1)] = o.r1;  Ai[SK(base+1)] = o.i1;
        Ar[SK(base+2)] = o.r2;  Ai[SK(base+2)] = o.i2;
        Ar[SK(base+3)] = o.r3;  Ai[SK(base+3)] = o.i3;
    }
    __syncthreads();
    stageLDS<1>(Ar,Ai,Br,Bi,    4, t4r,t4i,t4r,t4i, tid);       __syncthreads();
    stageLDS<1>(Br,Bi,Ar,Ai,   16, t16r,t16i,t16r,t16i, tid);   __syncthreads();
    stageLDS<1>(Ar,Ai,Br,Bi,   64, t64r,t64i,t64r,t64i, tid);   __syncthreads();
    stageLDS<1>(Br,Bi,Ar,Ai,  256, t256r,t256i,t256r,t256i, tid); __syncthreads();
    stageLDS<1>(Ar,Ai,Br,Bi, 1024, tAr,tAi,tBr,tBi, tid);       __syncthreads();
    // modes: k0 = Br[t], k1 = Bi[t];  A is now free -> pid scratch

    int* pidR = (int*)Ar;
    int* pidI = (int*)Ai;

    float aS0=0.f, aS1=0.f, aD00=0.f, aD11=0.f, aD01=0.f;
    float aX[(P > 0) ? 4*P : 1];
#pragma unroll
    for (int i = 0; i < ((P>0)?4*P:1); ++i) aX[i] = 0.f;

    float carry0 = 0.f, carry1 = 0.f;
#pragma unroll
    for (int u = 0; u < 8; ++u){
        int t  = tid + u*NTH;
        int t1 = (t+1 < TT) ? t+1 : TT-1;
        int t2 = (t+2 < TT) ? t+2 : TT-1;
        int t3 = (t+3 < TT) ? t+3 : TT-1;
        float b0 = Br[SK(t)], b1 = Br[SK(t1)], b2 = Br[SK(t2)], b3 = Br[SK(t3)];
        float i0 = Bi[SK(t)], i1 = Bi[SK(t1)], i2 = Bi[SK(t2)], i3 = Bi[SK(t3)];
        float e0 = b0*b0, e1 = i0*i0;
        aS0 += e0; aS1 += e1;
        aD00 += e0*e0; aD11 += e1*e1; aD01 += e0*e1;
#pragma unroll
        for (int l = 0; l < 2*P; ++l){
            float el = (u & 1) ? __high2float(est[l][u>>1]) : __low2float(est[l][u>>1]);
            aX[2*l]   += el * e0;
            aX[2*l+1] += el * e1;
        }
        if constexpr (P < 3){
            if ((u & 1) == 0){ carry0 = e0; carry1 = e1; }
            else {
                est[2*P][u>>1]   = __floats2half2_rn(carry0, e0);
                est[2*P+1][u>>1] = __floats2half2_rn(carry1, e1);
            }
        }
        if (t <= TT-4){
            pidR[t] = pattern_id(b0,b1,b2,b3);
            pidI[t] = pattern_id(i0,i1,i2,i3);
        }
    }
    __syncthreads();

    unsigned* h = hist + 576*((tid>>6) & 1);
#pragma unroll
    for (int u = 0; u < 8; ++u){
        int t = tid + u*NTH;
        if (t <= TT-5){
            atomicAdd(&h[pidR[t]*24 + pidR[t+1]], 1u);
            atomicAdd(&h[pidI[t]*24 + pidI[t+1]], 1u);
        }
    }
    __syncthreads();   // protects pid buffers (A) before next pair's stage-0 writes

    const int k0 = 2*P, k1 = 2*P+1;
    reduce_to(aS0,  res, k0, tid);
    reduce_to(aS1,  res, k1, tid);
    reduce_to(aD00, res, DIDX(k0,k0), tid);
    reduce_to(aD11, res, DIDX(k1,k1), tid);
    reduce_to(aD01, res, DIDX(k0,k1), tid);
#pragma unroll
    for (int l = 0; l < 2*P; ++l){
        reduce_to(aX[2*l],   res, DIDX(l,k0), tid);
        reduce_to(aX[2*l+1], res, DIDX(l,k1), tid);
    }
}

template<bool DIRECT>
__global__ __launch_bounds__(NTH, 4)
void fused_kernel(const float* __restrict__ hs, const float* __restrict__ pooled,
                  float* __restrict__ out){
    extern __shared__ float smem[];
    float* Ar = smem;
    float* Ai = smem + ARR;
    float* Br = smem + 2*ARR;
    float* Bi = smem + 3*ARR;
    unsigned* hist = (unsigned*)(smem + 4*ARR);   // 2 x 576
    float* res = smem + 4*ARR + 1152;             // 44

    const int tid = threadIdx.x;
    const int bg = blockIdx.x, b = bg >> 5, g = bg & 31;

    for (int i = tid; i < 1152; i += NTH) hist[i] = 0u;
    if (tid < 44) res[tid] = 0.f;

    // per-thread twiddles, inverse sign: u = e^{+i*pi*kk/(2Ns)}; kk fixed per thread per stage
    const float PI_F = 3.14159265358979323846f;
    float t4r,t4i,t16r,t16i,t64r,t64i,t256r,t256i,tAr,tAi,tBr,tBi;
    { float s,c;
      __sincosf(PI_F*(float)(tid &   3)/   8.f, &s,&c); t4r=c;   t4i=s;
      __sincosf(PI_F*(float)(tid &  15)/  32.f, &s,&c); t16r=c;  t16i=s;
      __sincosf(PI_F*(float)(tid &  63)/ 128.f, &s,&c); t64r=c;  t64i=s;
      __sincosf(PI_F*(float)(tid & 255)/ 512.f, &s,&c); t256r=c; t256i=s;
      __sincosf(PI_F*(float)tid        /2048.f, &s,&c); tAr=c;   tAi=s;
      __sincosf(PI_F*(float)(tid+512)  /2048.f, &s,&c); tBr=c;   tBi=s;
    }

    // load signal -> A (skewed)
    if (DIRECT){
        const float* base = hs + ((size_t)b * TT) * 512 + g * 16;
#pragma unroll
        for (int u = 0; u < 8; ++u){
            int t = tid + u*NTH;
            const float4* p = (const float4*)(base + (size_t)t * 512);
            float4 a = p[0], bb = p[1], cc = p[2], dd = p[3];
            float s = a.x+a.y+a.z+a.w + bb.x+bb.y+bb.z+bb.w
                    + cc.x+cc.y+cc.z+cc.w + dd.x+dd.y+dd.z+dd.w;
            Ar[SK(t)] = s * (1.0f/16.0f);
            Ai[SK(t)] = 0.f;
        }
    } else {
        const float* pp = pooled + (size_t)bg * TT;
#pragma unroll
        for (int u = 0; u < 8; ++u){
            int t = tid + u*NTH;
            Ar[SK(t)] = pp[t];
            Ai[SK(t)] = 0.f;
        }
    }
    __syncthreads();

    // forward FFT (SGN=-1): 6 radix-4 stages; final stage lands the spectrum in registers
    stageLDS<-1>(Ar,Ai,Br,Bi,   1, 1.f,0.f,1.f,0.f, tid);        __syncthreads();
    stageLDS<-1>(Br,Bi,Ar,Ai,   4, t4r,t4i,t4r,t4i, tid);        __syncthreads();
    stageLDS<-1>(Ar,Ai,Br,Bi,  16, t16r,t16i,t16r,t16i, tid);    __syncthreads();
    stageLDS<-1>(Br,Bi,Ar,Ai,  64, t64r,t64i,t64r,t64i, tid);    __syncthreads();
    stageLDS<-1>(Ar,Ai,Br,Bi, 256, t256r,t256i,t256r,t256i, tid);__syncthreads();

    float xr[8], xi[8];   // X[tid + 512*v]
    {
        C4 o;
        bf4<-1>(Br[SK(tid)],Bi[SK(tid)], Br[SK(tid+1024)],Bi[SK(tid+1024)],
                Br[SK(tid+2048)],Bi[SK(tid+2048)], Br[SK(tid+3072)],Bi[SK(tid+3072)],
                tAr,tAi,o);
        xr[0]=o.r0; xi[0]=o.i0; xr[2]=o.r1; xi[2]=o.i1;
        xr[4]=o.r2; xi[4]=o.i2; xr[6]=o.r3; xi[6]=o.i3;
        bf4<-1>(Br[SK(tid+512)],Bi[SK(tid+512)], Br[SK(tid+1536)],Bi[SK(tid+1536)],
                Br[SK(tid+2560)],Bi[SK(tid+2560)], Br[SK(tid+3584)],Bi[SK(tid+3584)],
                tBr,tBi,o);
        xr[1]=o.r0; xi[1]=o.i0; xr[3]=o.r1; xi[3]=o.i1;
        xr[5]=o.r2; xi[5]=o.i2; xr[7]=o.r3; xi[7]=o.i3;
    }
    // no sync needed: A's last reader (Ns=256 stage) is behind a barrier; pair-0 writes A next

    __half2 est[6][4];
    process_pair<0>(tid,Ar,Ai,Br,Bi,hist,res,xr,xi,est,t4r,t4i,t16r,t16i,t64r,t64i,t256r,t256i,tAr,tAi,tBr,tBi);
    process_pair<1>(tid,Ar,Ai,Br,Bi,hist,res,xr,xi,est,t4r,t4i,t16r,t16i,t64r,t64i,t256r,t256i,tAr,tAi,tBr,tBi);
    process_pair<2>(tid,Ar,Ai,Br,Bi,hist,res,xr,xi,est,t4r,t4i,t16r,t16i,t64r,t64i,t256r,t256i,tAr,tAi,tBr,tBi);
    process_pair<3>(tid,Ar,Ai,Br,Bi,hist,res,xr,xi,est,t4r,t4i,t16r,t16i,t64r,t64i,t256r,t256i,tAr,tAi,tBr,tBi);

    __syncthreads();   // res atomics + hist complete

    float* tm = out + (size_t)bg * 576;
    for (int i = tid; i < 576; i += NTH)
        tm[i] = (float)(hist[i] + hist[i+576]) * (1.0f/32736.0f);

    if (tid < 28){
        int q = tid, k = 0, cnt = 7, rem = q;
        while (rem >= cnt){ rem -= cnt; k++; cnt--; }
        int l = k + 1 + rem;
        float Sk = res[k], Sl = res[l];
        float Dkl = res[DIDX(k,l)], Dkk = res[DIDX(k,k)], Dll = res[DIDX(l,l)];
        float cov = Dkl - Sk*Sl*(1.0f/4096.0f);
        float vk = (Dkk - Sk*Sk*(1.0f/4096.0f)) * (1.0f/4095.0f);
        float vl = (Dll - Sl*Sl*(1.0f/4096.0f)) * (1.0f/4095.0f);
        float sk = fmaxf(sqrtf(fmaxf(vk, 0.f)), 1e-8f);
        float sl = fmaxf(sqrtf(fmaxf(vl, 0.f)), 1e-8f);
        out[294912 + (size_t)bg*28 + q] = cov * (1.0f/4096.0f) / (sk*sl);
    }
}

// Coalesced pooling: [B,T,512] -> [B,G,T] group means (unchanged, verified round 1)
__global__ __launch_bounds__(256)
void pool_kernel(const float* __restrict__ hs, float* __restrict__ pooled){
    __shared__ float tile[32][65];
    int blk = blockIdx.x;               // 16 b * 64 chunks
    int b   = blk >> 6;
    int t0  = (blk & 63) << 6;
    int tid = threadIdx.x;
    int lane = tid & 63, wid = tid >> 6;
#pragma unroll
    for (int i = 0; i < 16; ++i){
        int tl = wid + i*4;
        int t  = t0 + tl;
        const float4* p = (const float4*)(hs + ((size_t)b * TT + t) * 512);
        float4 a = p[lane];
        float4 c = p[lane + 64];
        float pa = a.x+a.y+a.z+a.w;
        float pc = c.x+c.y+c.z+c.w;
        pa += __shfl_xor(pa, 1); pa += __shfl_xor(pa, 2);
        pc += __shfl_xor(pc, 1); pc += __shfl_xor(pc, 2);
        if ((lane & 3) == 0){
            int gq = lane >> 2;
            tile[gq][tl]      = pa * (1.0f/16.0f);
            tile[gq + 16][tl] = pc * (1.0f/16.0f);
        }
    }
    __syncthreads();
    for (int idx = tid; idx < 2048; idx += 256){
        int g = idx >> 6, tt = idx & 63;
        pooled[((size_t)b * 32 + g) * TT + t0 + tt] = tile[g][tt];
    }
}

extern "C" void kernel_launch(void* const* d_in, const int* in_sizes, int n_in,
                              void* d_out, int out_size, void* d_ws, size_t ws_size,
                              hipStream_t stream){
    const float* hs = (const float*)d_in[0];
    float* out = (float*)d_out;
    const size_t poolBytes = (size_t)512 * TT * sizeof(float);   // 8.4 MB

    if (d_ws && ws_size >= poolBytes){
        float* pooled = (float*)d_ws;
        pool_kernel<<<1024, 256, 0, stream>>>(hs, pooled);
        hipFuncSetAttribute((const void*)fused_kernel<false>,
                            hipFuncAttributeMaxDynamicSharedMemorySize, SM_BYTES);
        fused_kernel<false><<<512, NTH, SM_BYTES, stream>>>(hs, pooled, out);
    } else {
        hipFuncSetAttribute((const void*)fused_kernel<true>,
                            hipFuncAttributeMaxDynamicSharedMemorySize, SM_BYTES);
        fused_kernel<true><<<512, NTH, SM_BYTES, stream>>>(hs, nullptr, out);
    }
}